// Round 1
// baseline (1177.827 us; speedup 1.0000x reference)
//
#include <hip/hip_runtime.h>
#include <stdint.h>

typedef unsigned int u32;
typedef unsigned long long u64;

#define QN 32        // queries
#define DIM 128      // embedding dim
#define TILE_R 512   // corpus rows per block
#define CHUNK 16     // d-floats staged per chunk
#define NCHUNK (DIM / CHUNK)
#define KSEL 10      // top-k

__device__ __forceinline__ u32 f2ord(float f) {
    u32 b = __float_as_uint(f);
    return b ^ (((int)b >> 31) | 0x80000000u);
}
__device__ __forceinline__ float ord2f(u32 e) {
    u32 b = (e & 0x80000000u) ? (e ^ 0x80000000u) : ~e;
    return __uint_as_float(b);
}

// Pass 1: each block scores TILE_R rows against all 32 queries, emits its
// local top-10 (score, idx) per query to workspace.
__launch_bounds__(256, 2)
__global__ void score_topk(const float* __restrict__ qry,
                           const float* __restrict__ corpus,
                           float* __restrict__ cand_s,
                           int* __restrict__ cand_i,
                           int n, int nb) {
    __shared__ float lds_q[QN * DIM];        // 16 KB, [q][d] packed
    __shared__ float lds_c[TILE_R * CHUNK];  // 32 KB, f4-swizzled: phys = d4 ^ ((r>>1)&3)

    const int tid = threadIdx.x;
    const int w = tid >> 6;   // wave id == query group (8 queries)
    const int l = tid & 63;
    const int tile_base = blockIdx.x * TILE_R;

    // stage queries (coalesced float4)
    {
        const float4* qg = (const float4*)qry;
        float4* ql = (float4*)lds_q;
        for (int i = tid; i < QN * DIM / 4; i += 256) ql[i] = qg[i];
    }

    float acc[8][8];   // [query][subrow]
    float ss[8];       // row sum-of-squares
#pragma unroll
    for (int a = 0; a < 8; ++a) {
        ss[a] = 0.f;
#pragma unroll
        for (int b = 0; b < 8; ++b) acc[a][b] = 0.f;
    }

#pragma unroll 1
    for (int c = 0; c < NCHUNK; ++c) {
        __syncthreads();  // prev chunk consumed (and queries visible at c=0)
        // wave w stages rows [w*128, w*128+128): 8 insts x (16 rows x 4 f4slots)
#pragma unroll
        for (int j = 0; j < 8; ++j) {
            int rt = w * 128 + j * 16 + (l >> 2);
            int grow = tile_base + rt;
            if (grow >= n) grow = n - 1;             // clamp; masked at epilogue
            int d4src = (l & 3) ^ ((rt >> 1) & 3);   // source-side swizzle
            const float* gp = corpus + (size_t)grow * DIM + c * CHUNK + d4src * 4;
            float* lp = lds_c + (w * 128 + j * 16) * CHUNK;  // wave-uniform base; HW adds lane*16
            __builtin_amdgcn_global_load_lds(
                (const __attribute__((address_space(1))) void*)gp,
                (__attribute__((address_space(3))) void*)lp, 16, 0, 0);
        }
        __syncthreads();  // drains vmcnt -> staged data visible

        const int qbase = (w * 8) * DIM + c * CHUNK;
#pragma unroll
        for (int d4 = 0; d4 < CHUNK / 4; ++d4) {
            float4 qv[8], cv[8];
#pragma unroll
            for (int qi = 0; qi < 8; ++qi)  // wave-uniform address -> LDS broadcast
                qv[qi] = *(const float4*)(lds_q + qbase + qi * DIM + d4 * 4);
#pragma unroll
            for (int s = 0; s < 8; ++s) {
                int r = s * 64 + l;
                int p = d4 ^ ((r >> 1) & 3);  // de-swizzle; conflict-free b128
                cv[s] = *(const float4*)(lds_c + r * CHUNK + p * 4);
            }
#pragma unroll
            for (int s = 0; s < 8; ++s) {
                ss[s] = fmaf(cv[s].x, cv[s].x, ss[s]);
                ss[s] = fmaf(cv[s].y, cv[s].y, ss[s]);
                ss[s] = fmaf(cv[s].z, cv[s].z, ss[s]);
                ss[s] = fmaf(cv[s].w, cv[s].w, ss[s]);
#pragma unroll
                for (int qi = 0; qi < 8; ++qi) {
                    acc[qi][s] = fmaf(qv[qi].x, cv[s].x, acc[qi][s]);
                    acc[qi][s] = fmaf(qv[qi].y, cv[s].y, acc[qi][s]);
                    acc[qi][s] = fmaf(qv[qi].z, cv[s].z, acc[qi][s]);
                    acc[qi][s] = fmaf(qv[qi].w, cv[s].w, acc[qi][s]);
                }
            }
        }
    }
    __syncthreads();

    // query inverse norms (butterfly sum over lanes; 2 floats/lane)
    float invq[8];
#pragma unroll
    for (int qi = 0; qi < 8; ++qi) {
        float2 v = *(const float2*)(lds_q + (w * 8 + qi) * DIM + 2 * l);
        float p = v.x * v.x + v.y * v.y;
#pragma unroll
        for (int off = 32; off; off >>= 1) p += __shfl_xor(p, off, 64);
        invq[qi] = rsqrtf(fmaxf(p, 1e-24f));
    }
    float invc[8];
#pragma unroll
    for (int s = 0; s < 8; ++s) invc[s] = rsqrtf(fmaxf(ss[s], 1e-24f));

    // per-query top-10 over this block's 512 rows (wave-wide argmax extraction)
#pragma unroll 1
    for (int qi = 0; qi < 8; ++qi) {
        const int qq = w * 8 + qi;
        u64 key[8];
#pragma unroll
        for (int s = 0; s < 8; ++s) {
            int gidx = tile_base + s * 64 + l;
            float sc = acc[qi][s] * invq[qi] * invc[s];
            u64 kk = ((u64)f2ord(sc) << 32) | (u32)(~(u32)gidx);  // tie -> lower idx
            key[s] = (gidx < n) ? kk : 0ull;
        }
#pragma unroll 1
        for (int rank = 0; rank < KSEL; ++rank) {
            u64 m = key[0];
#pragma unroll
            for (int s = 1; s < 8; ++s) m = (key[s] > m) ? key[s] : m;
            u64 win = m;
#pragma unroll
            for (int off = 1; off < 64; off <<= 1) {
                u64 o = (u64)__shfl_xor((long long)win, off, 64);
                if (o > win) win = o;
            }
            if (m == win) {  // unique owner (keys unique: distinct idx)
#pragma unroll
                for (int s = 0; s < 8; ++s)
                    if (key[s] == win) key[s] = 0ull;
            }
            if (l == 0) {
                int slot = (qq * nb + blockIdx.x) * KSEL + rank;
                cand_s[slot] = ord2f((u32)(win >> 32));
                cand_i[slot] = (int)(~(u32)win);
            }
        }
    }
}

// Pass 2: one wave per query merges nb*10 candidates -> global top-10.
__launch_bounds__(64)
__global__ void merge_topk(const float* __restrict__ cand_s,
                           const int* __restrict__ cand_i,
                           float* __restrict__ out, int nb, int qn) {
    const int q = blockIdx.x;
    const int l = threadIdx.x;
    const int total = nb * KSEL;
    const int base = q * total;

    u64 h[KSEL];  // descending sorted, h[9] = current 10th best
#pragma unroll
    for (int i = 0; i < KSEL; ++i) h[i] = 0ull;

    for (int j = l; j < total; j += 64) {
        float s = cand_s[base + j];
        int idx = cand_i[base + j];
        u64 kk = ((u64)f2ord(s) << 32) | (u32)(~(u32)idx);
        if (kk > h[KSEL - 1]) {  // rare: guarded unrolled sorted-insert
#pragma unroll
            for (int t = KSEL - 1; t > 0; --t) {
                if (kk > h[t]) h[t] = (kk > h[t - 1]) ? h[t - 1] : kk;
            }
            if (kk > h[0]) h[0] = kk;
        }
    }

    int p = 0;
#pragma unroll 1
    for (int rank = 0; rank < KSEL; ++rank) {
        u64 cand = (p < KSEL) ? h[p] : 0ull;
        u64 win = cand;
#pragma unroll
        for (int off = 1; off < 64; off <<= 1) {
            u64 o = (u64)__shfl_xor((long long)win, off, 64);
            if (o > win) win = o;
        }
        if (cand == win && win) ++p;  // unique owner advances
        if (l == 0) {
            out[q * KSEL + rank] = ord2f((u32)(win >> 32));
            out[qn * KSEL + q * KSEL + rank] = (float)(int)(~(u32)win);  // idx as float
        }
    }
}

extern "C" void kernel_launch(void* const* d_in, const int* in_sizes, int n_in,
                              void* d_out, int out_size, void* d_ws, size_t ws_size,
                              hipStream_t stream) {
    const float* qry = (const float*)d_in[0];
    const float* corpus = (const float*)d_in[1];
    const int qn = in_sizes[0] / DIM;  // 32
    const int n = in_sizes[1] / DIM;   // 1,000,000
    const int nb = (n + TILE_R - 1) / TILE_R;  // 1954

    float* cand_s = (float*)d_ws;
    int* cand_i = (int*)((char*)d_ws + (size_t)qn * nb * KSEL * sizeof(float));

    score_topk<<<dim3(nb), dim3(256), 0, stream>>>(qry, corpus, cand_s, cand_i, n, nb);
    merge_topk<<<dim3(qn), dim3(64), 0, stream>>>(cand_s, cand_i, (float*)d_out, nb, qn);
}

// Round 2
// 928.128 us; speedup vs baseline: 1.2690x; 1.2690x over previous
//
#include <hip/hip_runtime.h>
#include <stdint.h>

typedef unsigned int u32;
typedef unsigned long long u64;

#define QN 32        // queries
#define DIM 128      // embedding dim
#define TILE_R 512   // corpus rows per block
#define CHUNK 16     // d-floats staged per chunk
#define NCHUNK (DIM / CHUNK)
#define KSEL 10      // top-k
#define MCHUNKS 8    // merge1 chunks per query

__device__ __forceinline__ u32 f2ord(float f) {
    u32 b = __float_as_uint(f);
    return b ^ (((int)b >> 31) | 0x80000000u);
}
__device__ __forceinline__ float ord2f(u32 e) {
    u32 b = (e & 0x80000000u) ? (e ^ 0x80000000u) : ~e;
    return __uint_as_float(b);
}
__device__ __forceinline__ u64 shfl_xor_u64(u64 v, int off) {
    return (u64)__shfl_xor((long long)v, off, 64);
}
__device__ __forceinline__ u64 wave_max_u64(u64 v) {
#pragma unroll
    for (int off = 1; off < 64; off <<= 1) {
        u64 o = shfl_xor_u64(v, off);
        if (o > v) v = o;
    }
    return v;
}

// Pass 1: each block scores TILE_R rows against all 32 queries, emits its
// local top-10 packed (score,~idx) u64 keys per query to workspace.
// Register budget: acc 64 + ss 8 + qv 32 + cv 16 = 120 live -> no spills @128.
__launch_bounds__(256, 2)
__global__ void score_topk(const float* __restrict__ qry,
                           const float* __restrict__ corpus,
                           u64* __restrict__ cand_k,
                           int n, int nb) {
    __shared__ float lds_q[QN * DIM];        // 16 KB, [q][d] packed
    __shared__ float lds_c[TILE_R * CHUNK];  // 32 KB, f4-swizzled: phys = d4 ^ ((r>>1)&3)

    const int tid = threadIdx.x;
    const int w = tid >> 6;   // wave id == query group (8 queries)
    const int l = tid & 63;
    const int tile_base = blockIdx.x * TILE_R;

    // stage queries (coalesced float4)
    {
        const float4* qg = (const float4*)qry;
        float4* ql = (float4*)lds_q;
        for (int i = tid; i < QN * DIM / 4; i += 256) ql[i] = qg[i];
    }

    float acc[8][8];   // [query][subrow]
    float ss[8];       // row sum-of-squares
#pragma unroll
    for (int a = 0; a < 8; ++a) {
        ss[a] = 0.f;
#pragma unroll
        for (int b = 0; b < 8; ++b) acc[a][b] = 0.f;
    }

#pragma unroll 1
    for (int c = 0; c < NCHUNK; ++c) {
        __syncthreads();  // prev chunk consumed (and queries visible at c=0)
        // wave w stages rows [w*128, w*128+128): 8 insts x (16 rows x 4 f4slots)
#pragma unroll
        for (int j = 0; j < 8; ++j) {
            int rt = w * 128 + j * 16 + (l >> 2);
            int grow = tile_base + rt;
            if (grow >= n) grow = n - 1;             // clamp; masked at epilogue
            int d4src = (l & 3) ^ ((rt >> 1) & 3);   // source-side swizzle
            const float* gp = corpus + (size_t)grow * DIM + c * CHUNK + d4src * 4;
            float* lp = lds_c + (w * 128 + j * 16) * CHUNK;  // wave-uniform base; HW adds lane*16
            __builtin_amdgcn_global_load_lds(
                (const __attribute__((address_space(1))) void*)gp,
                (__attribute__((address_space(3))) void*)lp, 16, 0, 0);
        }
        __syncthreads();  // drains vmcnt -> staged data visible

        const int qbase = (w * 8) * DIM + c * CHUNK;
#pragma unroll 1
        for (int d4 = 0; d4 < CHUNK / 4; ++d4) {
            float4 qv[8];
#pragma unroll
            for (int qi = 0; qi < 8; ++qi)  // wave-uniform address -> LDS broadcast
                qv[qi] = *(const float4*)(lds_q + qbase + qi * DIM + d4 * 4);
#pragma unroll
            for (int g = 0; g < 2; ++g) {  // s in two groups of 4: cv live = 16 regs
                float4 cv[4];
#pragma unroll
                for (int s4 = 0; s4 < 4; ++s4) {
                    int r = (g * 4 + s4) * 64 + l;
                    int p = d4 ^ ((r >> 1) & 3);  // de-swizzle; conflict-free b128
                    cv[s4] = *(const float4*)(lds_c + r * CHUNK + p * 4);
                }
#pragma unroll
                for (int s4 = 0; s4 < 4; ++s4) {
                    const int s = g * 4 + s4;
                    ss[s] = fmaf(cv[s4].x, cv[s4].x, ss[s]);
                    ss[s] = fmaf(cv[s4].y, cv[s4].y, ss[s]);
                    ss[s] = fmaf(cv[s4].z, cv[s4].z, ss[s]);
                    ss[s] = fmaf(cv[s4].w, cv[s4].w, ss[s]);
#pragma unroll
                    for (int qi = 0; qi < 8; ++qi) {
                        acc[qi][s] = fmaf(qv[qi].x, cv[s4].x, acc[qi][s]);
                        acc[qi][s] = fmaf(qv[qi].y, cv[s4].y, acc[qi][s]);
                        acc[qi][s] = fmaf(qv[qi].z, cv[s4].z, acc[qi][s]);
                        acc[qi][s] = fmaf(qv[qi].w, cv[s4].w, acc[qi][s]);
                    }
                }
            }
        }
    }
    __syncthreads();

    // query inverse norms (butterfly sum over lanes; 2 floats/lane)
    float invq[8];
#pragma unroll
    for (int qi = 0; qi < 8; ++qi) {
        float2 v = *(const float2*)(lds_q + (w * 8 + qi) * DIM + 2 * l);
        float p = v.x * v.x + v.y * v.y;
#pragma unroll
        for (int off = 32; off; off >>= 1) p += __shfl_xor(p, off, 64);
        invq[qi] = rsqrtf(fmaxf(p, 1e-24f));
    }
    float invc[8];
#pragma unroll
    for (int s = 0; s < 8; ++s) invc[s] = rsqrtf(fmaxf(ss[s], 1e-24f));

    // per-query top-10 over this block's 512 rows (wave-wide argmax extraction)
#pragma unroll 1
    for (int qi = 0; qi < 8; ++qi) {
        const int qq = w * 8 + qi;
        u64 key[8];
#pragma unroll
        for (int s = 0; s < 8; ++s) {
            int gidx = tile_base + s * 64 + l;
            float sc = acc[qi][s] * invq[qi] * invc[s];
            u64 kk = ((u64)f2ord(sc) << 32) | (u32)(~(u32)gidx);  // tie -> lower idx
            key[s] = (gidx < n) ? kk : 0ull;
        }
#pragma unroll 1
        for (int rank = 0; rank < KSEL; ++rank) {
            u64 m = key[0];
#pragma unroll
            for (int s = 1; s < 8; ++s) m = (key[s] > m) ? key[s] : m;
            u64 win = wave_max_u64(m);
            if (m == win) {  // unique owner (keys unique: distinct idx)
#pragma unroll
                for (int s = 0; s < 8; ++s)
                    if (key[s] == win) key[s] = 0ull;
            }
            if (l == 0)
                cand_k[(qq * nb + blockIdx.x) * KSEL + rank] = win;
        }
    }
}

// Pass 2a: 32 queries x 8 chunks of blocks; each block reduces ~total/8
// candidates to top-10 via block-wide argmax extraction.
__launch_bounds__(256)
__global__ void merge1(const u64* __restrict__ cand_k,
                       u64* __restrict__ cand2, int total) {
    const int q = blockIdx.x >> 3;
    const int ch = blockIdx.x & 7;
    const int T = (total + MCHUNKS - 1) / MCHUNKS;
    const int start = ch * T;
    const int cnt = min(T, total - start);
    const int tid = threadIdx.x;
    const int w = tid >> 6;
    const int l = tid & 63;

    __shared__ u64 red[4];
    __shared__ u64 bwin_s;

    u64 K[KSEL];  // T <= 2443 <= 10*256
#pragma unroll
    for (int i = 0; i < KSEL; ++i) {
        int j = tid + i * 256;
        K[i] = (j < cnt) ? cand_k[(size_t)q * total + start + j] : 0ull;
    }

#pragma unroll 1
    for (int rank = 0; rank < KSEL; ++rank) {
        u64 m = K[0];
#pragma unroll
        for (int i = 1; i < KSEL; ++i) m = (K[i] > m) ? K[i] : m;
        u64 win = wave_max_u64(m);
        if (l == 0) red[w] = win;
        __syncthreads();
        if (tid == 0) {
            u64 b = red[0];
#pragma unroll
            for (int i = 1; i < 4; ++i) b = (red[i] > b) ? red[i] : b;
            bwin_s = b;
        }
        __syncthreads();
        u64 bwin = bwin_s;
#pragma unroll
        for (int i = 0; i < KSEL; ++i)
            if (K[i] == bwin) K[i] = 0ull;
        if (tid == 0) cand2[(size_t)(q * MCHUNKS + ch) * KSEL + rank] = bwin;
        __syncthreads();  // protect red/bwin_s for next round
    }
}

// Pass 2b: one wave per query merges 80 candidates -> final top-10.
__launch_bounds__(64)
__global__ void merge2(const u64* __restrict__ cand2,
                       float* __restrict__ out, int qn) {
    const int q = blockIdx.x;
    const int l = threadIdx.x;
    const int total = MCHUNKS * KSEL;  // 80

    u64 K[2];
#pragma unroll
    for (int i = 0; i < 2; ++i) {
        int j = l + i * 64;
        K[i] = (j < total) ? cand2[(size_t)q * total + j] : 0ull;
    }

#pragma unroll 1
    for (int rank = 0; rank < KSEL; ++rank) {
        u64 m = (K[0] > K[1]) ? K[0] : K[1];
        u64 win = wave_max_u64(m);
#pragma unroll
        for (int i = 0; i < 2; ++i)
            if (K[i] == win) K[i] = 0ull;
        if (l == 0) {
            out[q * KSEL + rank] = ord2f((u32)(win >> 32));
            out[qn * KSEL + q * KSEL + rank] = (float)(int)(~(u32)win);  // idx as float
        }
    }
}

extern "C" void kernel_launch(void* const* d_in, const int* in_sizes, int n_in,
                              void* d_out, int out_size, void* d_ws, size_t ws_size,
                              hipStream_t stream) {
    const float* qry = (const float*)d_in[0];
    const float* corpus = (const float*)d_in[1];
    const int qn = in_sizes[0] / DIM;  // 32
    const int n = in_sizes[1] / DIM;   // 1,000,000
    const int nb = (n + TILE_R - 1) / TILE_R;  // 1954
    const int total = nb * KSEL;       // candidates per query

    u64* cand_k = (u64*)d_ws;
    u64* cand2 = cand_k + (size_t)qn * total;

    score_topk<<<dim3(nb), dim3(256), 0, stream>>>(qry, corpus, cand_k, n, nb);
    merge1<<<dim3(qn * MCHUNKS), dim3(256), 0, stream>>>(cand_k, cand2, total);
    merge2<<<dim3(qn), dim3(64), 0, stream>>>(cand2, (float*)d_out, qn);
}

// Round 3
// 869.225 us; speedup vs baseline: 1.3550x; 1.0678x over previous
//
#include <hip/hip_runtime.h>
#include <stdint.h>

typedef unsigned int u32;
typedef unsigned long long u64;

#define QN 32        // queries
#define DIM 128      // embedding dim
#define TILE_R 512   // corpus rows per block
#define CHUNK 16     // d-floats staged per chunk
#define NCHUNK (DIM / CHUNK)
#define KSEL 10      // top-k
#define MCHUNKS 8    // merge1 chunks per query

__device__ __forceinline__ u32 f2ord(float f) {
    u32 b = __float_as_uint(f);
    return b ^ (((int)b >> 31) | 0x80000000u);
}
__device__ __forceinline__ float ord2f(u32 e) {
    u32 b = (e & 0x80000000u) ? (e ^ 0x80000000u) : ~e;
    return __uint_as_float(b);
}
__device__ __forceinline__ u64 shfl_xor_u64(u64 v, int off) {
    return (u64)__shfl_xor((long long)v, off, 64);
}
__device__ __forceinline__ u64 wave_max_u64(u64 v) {
#pragma unroll
    for (int off = 1; off < 64; off <<= 1) {
        u64 o = shfl_xor_u64(v, off);
        if (o > v) v = o;
    }
    return v;
}

// Pass 1: each block scores TILE_R rows against all 32 queries, emits its
// local top-10 packed (score,~idx) u64 keys per query to workspace.
// CRITICAL: no dynamic indexing of acc/invq anywhere — dynamic VGPR indexing
// demotes the accumulator tile to scratch (R2: VGPR=84, 1.02 GB scratch
// writeback). Epilogue qi loop is fully unrolled.
__launch_bounds__(256, 2)
__global__ void score_topk(const float* __restrict__ qry,
                           const float* __restrict__ corpus,
                           u64* __restrict__ cand_k,
                           int n, int nb) {
    __shared__ float lds_q[QN * DIM];        // 16 KB, [q][d] packed
    __shared__ float lds_c[TILE_R * CHUNK];  // 32 KB, f4-swizzled: phys = d4 ^ ((r>>1)&3)

    const int tid = threadIdx.x;
    const int w = tid >> 6;   // wave id == query group (8 queries)
    const int l = tid & 63;
    const int tile_base = blockIdx.x * TILE_R;

    // stage queries (coalesced float4)
    {
        const float4* qg = (const float4*)qry;
        float4* ql = (float4*)lds_q;
        for (int i = tid; i < QN * DIM / 4; i += 256) ql[i] = qg[i];
    }

    float acc[8][8];   // [query][subrow] — must stay in VGPRs
    float ss[8];       // row sum-of-squares
#pragma unroll
    for (int a = 0; a < 8; ++a) {
        ss[a] = 0.f;
#pragma unroll
        for (int b = 0; b < 8; ++b) acc[a][b] = 0.f;
    }

#pragma unroll 1
    for (int c = 0; c < NCHUNK; ++c) {
        __syncthreads();  // prev chunk consumed (and queries visible at c=0)
        // wave w stages rows [w*128, w*128+128): 8 insts x (16 rows x 4 f4slots)
#pragma unroll
        for (int j = 0; j < 8; ++j) {
            int rt = w * 128 + j * 16 + (l >> 2);
            int grow = tile_base + rt;
            if (grow >= n) grow = n - 1;             // clamp; masked at epilogue
            int d4src = (l & 3) ^ ((rt >> 1) & 3);   // source-side swizzle
            const float* gp = corpus + (size_t)grow * DIM + c * CHUNK + d4src * 4;
            float* lp = lds_c + (w * 128 + j * 16) * CHUNK;  // wave-uniform base; HW adds lane*16
            __builtin_amdgcn_global_load_lds(
                (const __attribute__((address_space(1))) void*)gp,
                (__attribute__((address_space(3))) void*)lp, 16, 0, 0);
        }
        __syncthreads();  // drains vmcnt -> staged data visible

        const int qbase = (w * 8) * DIM + c * CHUNK;
#pragma unroll 1
        for (int d4 = 0; d4 < CHUNK / 4; ++d4) {
            float4 qv[8];
#pragma unroll
            for (int qi = 0; qi < 8; ++qi)  // wave-uniform address -> LDS broadcast
                qv[qi] = *(const float4*)(lds_q + qbase + qi * DIM + d4 * 4);
#pragma unroll
            for (int g = 0; g < 2; ++g) {  // s in two groups of 4: cv live = 16 regs
                float4 cv[4];
#pragma unroll
                for (int s4 = 0; s4 < 4; ++s4) {
                    int r = (g * 4 + s4) * 64 + l;
                    int p = d4 ^ ((r >> 1) & 3);  // de-swizzle; conflict-free b128
                    cv[s4] = *(const float4*)(lds_c + r * CHUNK + p * 4);
                }
#pragma unroll
                for (int s4 = 0; s4 < 4; ++s4) {
                    const int s = g * 4 + s4;
                    ss[s] = fmaf(cv[s4].x, cv[s4].x, ss[s]);
                    ss[s] = fmaf(cv[s4].y, cv[s4].y, ss[s]);
                    ss[s] = fmaf(cv[s4].z, cv[s4].z, ss[s]);
                    ss[s] = fmaf(cv[s4].w, cv[s4].w, ss[s]);
#pragma unroll
                    for (int qi = 0; qi < 8; ++qi) {
                        acc[qi][s] = fmaf(qv[qi].x, cv[s4].x, acc[qi][s]);
                        acc[qi][s] = fmaf(qv[qi].y, cv[s4].y, acc[qi][s]);
                        acc[qi][s] = fmaf(qv[qi].z, cv[s4].z, acc[qi][s]);
                        acc[qi][s] = fmaf(qv[qi].w, cv[s4].w, acc[qi][s]);
                    }
                }
            }
        }
    }
    __syncthreads();

    // query inverse norms (butterfly sum over lanes; 2 floats/lane)
    float invq[8];
#pragma unroll
    for (int qi = 0; qi < 8; ++qi) {
        float2 v = *(const float2*)(lds_q + (w * 8 + qi) * DIM + 2 * l);
        float p = v.x * v.x + v.y * v.y;
#pragma unroll
        for (int off = 32; off; off >>= 1) p += __shfl_xor(p, off, 64);
        invq[qi] = rsqrtf(fmaxf(p, 1e-24f));
    }
    float invc[8];
#pragma unroll
    for (int s = 0; s < 8; ++s) invc[s] = rsqrtf(fmaxf(ss[s], 1e-24f));

    // per-query top-10 over this block's 512 rows (wave-wide argmax extraction)
    // FULLY UNROLLED over qi: all acc/invq indices static -> stays in VGPRs.
#pragma unroll
    for (int qi = 0; qi < 8; ++qi) {
        const int qq = w * 8 + qi;
        u64 key[8];
#pragma unroll
        for (int s = 0; s < 8; ++s) {
            int gidx = tile_base + s * 64 + l;
            float sc = acc[qi][s] * invq[qi] * invc[s];
            u64 kk = ((u64)f2ord(sc) << 32) | (u32)(~(u32)gidx);  // tie -> lower idx
            key[s] = (gidx < n) ? kk : 0ull;
        }
#pragma unroll 1
        for (int rank = 0; rank < KSEL; ++rank) {
            u64 m = key[0];
#pragma unroll
            for (int s = 1; s < 8; ++s) m = (key[s] > m) ? key[s] : m;
            u64 win = wave_max_u64(m);
            if (m == win) {  // unique owner (keys unique: distinct idx)
#pragma unroll
                for (int s = 0; s < 8; ++s)
                    if (key[s] == win) key[s] = 0ull;
            }
            if (l == 0)
                cand_k[(qq * nb + blockIdx.x) * KSEL + rank] = win;
        }
    }
}

// Pass 2a: one wave per (query, chunk); ~2443 candidates -> top-10.
// Per-thread guarded sorted-insert (no barriers), then 10 wave extractions.
__launch_bounds__(64)
__global__ void merge1(const u64* __restrict__ cand_k,
                       u64* __restrict__ cand2, int total) {
    const int q = blockIdx.x >> 3;
    const int ch = blockIdx.x & 7;
    const int T = (total + MCHUNKS - 1) / MCHUNKS;
    const int start = ch * T;
    const int cnt = min(T, total - start);
    const int l = threadIdx.x;

    u64 h[KSEL];  // descending sorted, h[9] = current 10th best
#pragma unroll
    for (int i = 0; i < KSEL; ++i) h[i] = 0ull;

    for (int j = l; j < cnt; j += 64) {
        u64 kk = cand_k[(size_t)q * total + start + j];
        if (kk > h[KSEL - 1]) {  // rare: guarded unrolled sorted-insert
#pragma unroll
            for (int t = KSEL - 1; t > 0; --t) {
                if (kk > h[t]) h[t] = (kk > h[t - 1]) ? h[t - 1] : kk;
            }
            if (kk > h[0]) h[0] = kk;
        }
    }

    int p = 0;
#pragma unroll 1
    for (int rank = 0; rank < KSEL; ++rank) {
        u64 cand = (p < KSEL) ? h[p] : 0ull;
        u64 win = wave_max_u64(cand);
        if (cand == win && win) ++p;  // unique owner advances
        if (l == 0) cand2[(size_t)(q * MCHUNKS + ch) * KSEL + rank] = win;
    }
}

// Pass 2b: one wave per query merges 80 candidates -> final top-10.
__launch_bounds__(64)
__global__ void merge2(const u64* __restrict__ cand2,
                       float* __restrict__ out, int qn) {
    const int q = blockIdx.x;
    const int l = threadIdx.x;
    const int total = MCHUNKS * KSEL;  // 80

    u64 K[2];
#pragma unroll
    for (int i = 0; i < 2; ++i) {
        int j = l + i * 64;
        K[i] = (j < total) ? cand2[(size_t)q * total + j] : 0ull;
    }

#pragma unroll 1
    for (int rank = 0; rank < KSEL; ++rank) {
        u64 m = (K[0] > K[1]) ? K[0] : K[1];
        u64 win = wave_max_u64(m);
#pragma unroll
        for (int i = 0; i < 2; ++i)
            if (K[i] == win) K[i] = 0ull;
        if (l == 0) {
            out[q * KSEL + rank] = ord2f((u32)(win >> 32));
            out[qn * KSEL + q * KSEL + rank] = (float)(int)(~(u32)win);  // idx as float
        }
    }
}

extern "C" void kernel_launch(void* const* d_in, const int* in_sizes, int n_in,
                              void* d_out, int out_size, void* d_ws, size_t ws_size,
                              hipStream_t stream) {
    const float* qry = (const float*)d_in[0];
    const float* corpus = (const float*)d_in[1];
    const int qn = in_sizes[0] / DIM;  // 32
    const int n = in_sizes[1] / DIM;   // 1,000,000
    const int nb = (n + TILE_R - 1) / TILE_R;  // 1954
    const int total = nb * KSEL;       // candidates per query

    u64* cand_k = (u64*)d_ws;
    u64* cand2 = cand_k + (size_t)qn * total;

    score_topk<<<dim3(nb), dim3(256), 0, stream>>>(qry, corpus, cand_k, n, nb);
    merge1<<<dim3(qn * MCHUNKS), dim3(64), 0, stream>>>(cand_k, cand2, total);
    merge2<<<dim3(qn), dim3(64), 0, stream>>>(cand2, (float*)d_out, qn);
}